// Round 11
// baseline (23.519 us; speedup 1.0000x reference)
//
#include <hip/hip_runtime.h>

#define NG      4000
#define EPG     512
#define CSTRIDE 36   // ints per Cnt row: 16B-aligned rows+q4 slices -> b128 reads, uniform banks

__device__ inline float dot4(const float4 a, const float4 b) {
    return a.x * b.x + a.y * b.y + a.z * b.z + a.w * b.w;
}

// ---- prep: p = W1*(W2*(W3*1)); out[0..63]=p, out[64]=b1.q2, out[65]=b2.w3, out[66]=64*sum(b3)
__global__ __launch_bounds__(256) void prep_vec(
    const float* __restrict__ W1, const float* __restrict__ b1,
    const float* __restrict__ W2, const float* __restrict__ b2,
    const float* __restrict__ W3, const float* __restrict__ b3,
    float* __restrict__ out)
{
    __shared__ float w3[64], q2[64];
    const int t  = threadIdx.x;
    const int rg = t >> 4;           // row = 16*j + rg for float4 #j
    const int l16 = t & 15;

    const float4* W1_4 = (const float4*)W1;
    const float4* W2_4 = (const float4*)W2;
    const float4* W3_4 = (const float4*)W3;
    float4 a3[4], a2[4], a1[4];
    #pragma unroll
    for (int j = 0; j < 4; ++j) a3[j] = W3_4[t + 256 * j];
    #pragma unroll
    for (int j = 0; j < 4; ++j) a2[j] = W2_4[t + 256 * j];
    #pragma unroll
    for (int j = 0; j < 4; ++j) a1[j] = W1_4[t + 256 * j];
    float bb1 = 0.f, bb2 = 0.f, bb3 = 0.f;
    if (t < 64) { bb1 = b1[t]; bb2 = b2[t]; bb3 = b3[t]; }

    #pragma unroll
    for (int j = 0; j < 4; ++j) {
        float s = a3[j].x + a3[j].y + a3[j].z + a3[j].w;
        s += __shfl_down(s, 8, 16);
        s += __shfl_down(s, 4, 16);
        s += __shfl_down(s, 2, 16);
        s += __shfl_down(s, 1, 16);
        if (l16 == 0) w3[16 * j + rg] = s;
    }
    __syncthreads();

    {
        const float4 wc = ((const float4*)w3)[l16];
        #pragma unroll
        for (int j = 0; j < 4; ++j) {
            float s = dot4(a2[j], wc);
            s += __shfl_down(s, 8, 16);
            s += __shfl_down(s, 4, 16);
            s += __shfl_down(s, 2, 16);
            s += __shfl_down(s, 1, 16);
            if (l16 == 0) q2[16 * j + rg] = s;
        }
    }
    __syncthreads();

    {
        const float4 qc = ((const float4*)q2)[l16];
        #pragma unroll
        for (int j = 0; j < 4; ++j) {
            float s = dot4(a1[j], qc);
            s += __shfl_down(s, 8, 16);
            s += __shfl_down(s, 4, 16);
            s += __shfl_down(s, 2, 16);
            s += __shfl_down(s, 1, 16);
            if (l16 == 0) out[16 * j + rg] = s;
        }
    }

    if (t < 64) {
        float t1 = bb1 * q2[t];
        float t2 = bb2 * w3[t];
        float t3 = bb3;
        #pragma unroll
        for (int off = 32; off > 0; off >>= 1) {
            t1 += __shfl_down(t1, off, 64);
            t2 += __shfl_down(t2, off, 64);
            t3 += __shfl_down(t3, off, 64);
        }
        if (t == 0) { out[64] = t1; out[65] = t2; out[66] = 64.f * t3; }
    }
}

// ---- main: wide gather matvec with b128 LDS reads, 8 blocks/CU, 6 barriers ----
__global__ __launch_bounds__(256, 8) void gcn3_collapse3(
    const float* __restrict__ x, const int* __restrict__ ei,
    const float* __restrict__ pv, float* __restrict__ y, int etot)
{
    __shared__ int   Cnt[64 * CSTRIDE];   // packed u16x2 counts, Cnt[s][d]  (9216 B)
    __shared__ int   deg4[4][64];         // per-wave degree copies          (1024 B)
    __shared__ float dinv[64], zdA[64], zdB[64], u1[64], u2[64], u3[64], xp[64];

    const int g = blockIdx.x, t = threadIdx.x;
    const int w = t >> 6;
    const int base = g * 64;
    const int row = t >> 2, q4 = t & 3;

    // x loads first: thread t covers 64 consecutive bytes -> wave reads 4 KB coalesced
    const float4* xg = (const float4*)(x + (size_t)g * 4096 + row * 64 + q4 * 16);
    const float4 xr0 = xg[0], xr1 = xg[1], xr2 = xg[2], xr3 = xg[3];

    // edges (2 per thread, coalesced)
    const int2 sv = *(const int2*)(ei + (size_t)g * EPG + 2 * t);
    const int2 dv = *(const int2*)(ei + (size_t)etot + (size_t)g * EPG + 2 * t);

    // p slice (same 256 B for all blocks -> L1-hot)
    const float4* pp = (const float4*)(pv + q4 * 16);
    const float4 p0 = pp[0], p1 = pp[1], p2 = pp[2], p3 = pp[3];

    // zero Cnt + deg4
    {
        const int4 z = {0, 0, 0, 0};
        int4* c4 = (int4*)Cnt;
        #pragma unroll 1
        for (int i = t; i < (64 * CSTRIDE) / 4; i += 256) c4[i] = z;
        ((int*)deg4)[t] = 0;
    }
    __syncthreads();                                   // B1

    // deterministic integer scatter (per-wave deg copies cut contention 4x)
    {
        const int sa = sv.x - base, da = dv.x - base;
        const int sb = sv.y - base, db = dv.y - base;
        atomicAdd(&deg4[w][da], 1);
        atomicAdd(&deg4[w][db], 1);
        atomicAdd(&Cnt[sa * CSTRIDE + (da >> 1)], 1 << ((da & 1) * 16));
        atomicAdd(&Cnt[sb * CSTRIDE + (db >> 1)], 1 << ((db & 1) * 16));
    }

    // xp[r] = dot(x[r,:], p) — register math + 4-lane shfl reduce
    {
        float part = dot4(xr0, p0) + dot4(xr1, p1) + dot4(xr2, p2) + dot4(xr3, p3);
        part += __shfl_down(part, 2, 4);
        part += __shfl_down(part, 1, 4);
        if (q4 == 0) xp[row] = part;
    }
    __syncthreads();                                   // B2 (covers atomics + xp)

    if (t < 64) {
        const int ds = deg4[0][t] + deg4[1][t] + deg4[2][t] + deg4[3][t];
        const float di = rsqrtf((float)(ds + 1));      // +1 = self-loop
        dinv[t] = di;
        zdA[t] = di;                                   // zd for pass 1 (z = 1)
    }
    __syncthreads();                                   // B3

    // u-pass: vectorized gather matvec — 2 x int4 Cnt + 4 x float4 zin per thread
    auto upass = [&](const float* zin, float* zout, const float* uprev, float* u) {
        const int4* rp = (const int4*)(Cnt + row * CSTRIDE + q4 * 8);
        const int4 c0 = rp[0], c1 = rp[1];
        const float4* zp = (const float4*)(zin + q4 * 16);
        const float4 z0 = zp[0], z1 = zp[1], z2 = zp[2], z3 = zp[3];
        // counts: int j of this slice covers d = q4*16 + 2j (lo16), +1 (hi16); ascending d order
        float acc = 0.f;
        acc += (float)((unsigned)c0.x & 0xffffu) * z0.x + (float)((unsigned)c0.x >> 16) * z0.y;
        acc += (float)((unsigned)c0.y & 0xffffu) * z0.z + (float)((unsigned)c0.y >> 16) * z0.w;
        acc += (float)((unsigned)c0.z & 0xffffu) * z1.x + (float)((unsigned)c0.z >> 16) * z1.y;
        acc += (float)((unsigned)c0.w & 0xffffu) * z1.z + (float)((unsigned)c0.w >> 16) * z1.w;
        acc += (float)((unsigned)c1.x & 0xffffu) * z2.x + (float)((unsigned)c1.x >> 16) * z2.y;
        acc += (float)((unsigned)c1.y & 0xffffu) * z2.z + (float)((unsigned)c1.y >> 16) * z2.w;
        acc += (float)((unsigned)c1.z & 0xffffu) * z3.x + (float)((unsigned)c1.z >> 16) * z3.y;
        acc += (float)((unsigned)c1.w & 0xffffu) * z3.z + (float)((unsigned)c1.w >> 16) * z3.w;
        acc += __shfl_down(acc, 2, 4);
        acc += __shfl_down(acc, 1, 4);
        if (q4 == 0) {
            const float di = dinv[row];
            const float zp_ = uprev ? uprev[row] : 1.0f;
            const float uv = di * acc + di * di * zp_;
            u[row] = uv;
            if (zout) zout[row] = di * uv;             // fused zd update (other buffer)
        }
        __syncthreads();
    };

    upass(zdA, zdB, nullptr, u1);                      // B4
    upass(zdB, zdA, u1,      u2);                      // B5
    upass(zdA, nullptr, u2,  u3);                      // B6

    // final: r = u3 . xp, s1 = sum(u1), s2 = sum(u2)
    if (t < 64) {
        float r  = u3[t] * xp[t];
        float a1 = u1[t];
        float a2 = u2[t];
        #pragma unroll
        for (int off = 32; off > 0; off >>= 1) {
            r  += __shfl_down(r,  off, 64);
            a1 += __shfl_down(a1, off, 64);
            a2 += __shfl_down(a2, off, 64);
        }
        if (t == 0) {
            const float beta1 = pv[64], beta2 = pv[65], beta3 = pv[66];
            y[g] = (r + a2 * beta1 + a1 * beta2 + beta3) * (1.0f / 4096.0f);
        }
    }
}

extern "C" void kernel_launch(void* const* d_in, const int* in_sizes, int n_in,
                              void* d_out, int out_size, void* d_ws, size_t ws_size,
                              hipStream_t stream) {
    const float* x  = (const float*)d_in[0];
    const int*   ei = (const int*)  d_in[1];
    const float* W1 = (const float*)d_in[2];
    const float* b1 = (const float*)d_in[3];
    const float* W2 = (const float*)d_in[4];
    const float* b2 = (const float*)d_in[5];
    const float* W3 = (const float*)d_in[6];
    const float* b3 = (const float*)d_in[7];
    float* y = (float*)d_out;
    const int etot = in_sizes[1] / 2;     // 2,048,000

    float* pv = (float*)d_ws;             // 67 floats
    hipLaunchKernelGGL(prep_vec, dim3(1), dim3(256), 0, stream,
                       W1, b1, W2, b2, W3, b3, pv);
    hipLaunchKernelGGL(gcn3_collapse3, dim3(NG), dim3(256), 0, stream,
                       x, ei, pv, y, etot);
}